// Round 16
// baseline (3295.642 us; speedup 1.0000x reference)
//
#include <hip/hip_runtime.h>
#include <hip/hip_bf16.h>
#include <math.h>

// ---------------- model dims ----------------
#define Bsz 32
#define Cdim 768
#define Mdim 3072
#define Ldim 12
#define NTOK 210            // real tokens per image: 14*(14+1)
#define NTOKP 256           // padded tokens per image
#define TPAD (Bsz*NTOKP)    // 8192 padded token rows
#define NPATCH 196
#define PROWS (Bsz*NPATCH)  // 6272 = 49*128
#define NCls 1000

typedef __hip_bfloat16 bf16;
typedef __attribute__((ext_vector_type(8))) short bfrag;   // 8 bf16 = 4 VGPR
typedef __attribute__((ext_vector_type(4))) float f32x4;

enum { EPI_NONE = 0, EPI_PHI = 1, EPI_GELU = 2, EPI_RESID = 3 };

__device__ __forceinline__ void gl_lds16(const void* g, void* l) {
    __builtin_amdgcn_global_load_lds(
        (const __attribute__((address_space(1))) unsigned*)g,
        (__attribute__((address_space(3))) unsigned*)l, 16, 0, 0);
}

__device__ __forceinline__ void stv(float* p, float v) { *p = v; }
__device__ __forceinline__ void stv(bf16* p, float v)  { *p = __float2bfloat16(v); }

// ---- XCD-aware bijective swizzle of a flat block id over nwg blocks ----
__device__ __forceinline__ int xcd_flat(int flat, int nwg)
{
    int q8 = nwg >> 3, r8 = nwg & 7;
    int xcd = flat & 7, loc = flat >> 3;
    return ((xcd < r8) ? xcd * (q8 + 1) : r8 * (q8 + 1) + (xcd - r8) * q8) + loc;
}

// -------------------------------------------------------------------------
// R7 K-loop body (proven 3092us config): 128x128 tile, BK=64, 2-slot dbuf
// (64KB LDS), counted vmcnt(8), chunk-XOR LDS swizzle (0 conflicts),
// T5 setprio. Factored as a device function so single and dual-dispatch
// kernels share the exact same code.
// C[m,n] = sum_k A[m,k]*B[n,k] (+bias) + epilogue. N%128==0, K%64==0.
// zc: EPI_PHI only — output cols gn>=zc written as 0 (token-pad cols).
// -------------------------------------------------------------------------
template<int EPI, bool HAS_BIAS, typename OUTT>
__device__ __forceinline__
void bt_body(bf16* sh, const bf16* __restrict__ A, const bf16* __restrict__ B,
             const float* __restrict__ bias, OUTT* __restrict__ C,
             int N, int K, int m0, int n0, int zc)
{
    const int tid  = threadIdx.x;
    const int lane = tid & 63, wid = tid >> 6;
    const int wr = wid >> 1, wc = wid & 1;
    const int lr = lane & 15, lg = lane >> 4;

    f32x4 acc[4][4];
    #pragma unroll
    for (int i = 0; i < 4; ++i)
        #pragma unroll
        for (int j = 0; j < 4; ++j)
            acc[i][j] = f32x4{0.f, 0.f, 0.f, 0.f};

    // staging: linear LDS dest; inverse-swizzled GLOBAL 16B chunk (rule 21)
    const int srow = tid >> 3;                                   // 0..31
    const int scol = ((tid & 7) ^ ((tid >> 3) & 7)) * 8;         // elems
    const bf16* gA = A + (long)(m0 + srow) * K + scol;
    const bf16* gB = B + (long)(n0 + srow) * K + scol;

    auto stage = [&](int slot) {
        bf16* s = sh + slot * 16384;
        #pragma unroll
        for (int L = 0; L < 4; ++L)
            gl_lds16(gA + (long)(L * 32) * K, s + L * 2048 + tid * 8);
        #pragma unroll
        for (int L = 0; L < 4; ++L)
            gl_lds16(gB + (long)(L * 32) * K, s + 8192 + L * 2048 + tid * 8);
        gA += 64; gB += 64;
    };

    // fragment reads: phys 16B-chunk = logical ^ (row&7)
    const int rxor = lr & 7;
    const int arow = (wr * 64 + lr) * 64;
    const int brow = (wc * 64 + lr) * 64;

    const int kt = K >> 6;
    stage(0);

    for (int t = 0; t < kt; ++t) {
        if (t + 1 < kt) {
            stage((t + 1) & 1);
            asm volatile("s_waitcnt vmcnt(8)" ::: "memory");   // tile t landed
        } else {
            asm volatile("s_waitcnt vmcnt(0)" ::: "memory");
        }
        __builtin_amdgcn_s_barrier();

        const bf16* Ab = sh + (t & 1) * 16384;
        const bf16* Bb = Ab + 8192;
        bfrag a[4][2], b[4][2];
        #pragma unroll
        for (int i = 0; i < 4; ++i)
            #pragma unroll
            for (int ks = 0; ks < 2; ++ks)
                a[i][ks] = *(const bfrag*)(Ab + arow + i * 1024 + ((ks * 4 + lg) ^ rxor) * 8);
        #pragma unroll
        for (int j = 0; j < 4; ++j)
            #pragma unroll
            for (int ks = 0; ks < 2; ++ks)
                b[j][ks] = *(const bfrag*)(Bb + brow + j * 1024 + ((ks * 4 + lg) ^ rxor) * 8);

        __builtin_amdgcn_s_setprio(1);
        #pragma unroll
        for (int ks = 0; ks < 2; ++ks)
            #pragma unroll
            for (int i = 0; i < 4; ++i)
                #pragma unroll
                for (int j = 0; j < 4; ++j)
                    acc[i][j] = __builtin_amdgcn_mfma_f32_16x16x32_bf16(a[i][ks], b[j][ks], acc[i][j], 0, 0, 0);
        __builtin_amdgcn_s_setprio(0);
        __builtin_amdgcn_s_barrier();
    }

    // epilogue: C/D mapping col=lane&15, row=(lane>>4)*4+reg  [m89/m91]
    const int cidx  = lane & 15;
    const int rbase = (lane >> 4) * 4;
    #pragma unroll
    for (int i = 0; i < 4; ++i) {
        #pragma unroll
        for (int j = 0; j < 4; ++j) {
            const int gn = n0 + wc * 64 + j * 16 + cidx;
            float bv = HAS_BIAS ? bias[gn] : 0.f;
            #pragma unroll
            for (int r = 0; r < 4; ++r) {
                const int gm = m0 + wr * 64 + i * 16 + rbase + r;
                float v = acc[i][j][r] + bv;
                long idx = (long)gm * N + gn;
                if (EPI == EPI_PHI) {
                    v = (v > 0.f) ? (v + 1.f) : expf(v);
                    if (gn >= zc) v = 0.f;           // zero token-pad cols
                }
                if (EPI == EPI_GELU)  v = 0.5f * v * (1.f + erff(v * 0.70710678118654752f));
                if (EPI == EPI_RESID) v += ((const float*)C)[idx];
                stv(&C[idx], v);
            }
        }
    }
}

// ---- single-GEMM kernel (R7 exact semantics) ----
template<int EPI, bool HAS_BIAS, typename OUTT>
__global__ __launch_bounds__(256, 2)
void gemm_bt(const bf16* __restrict__ A, const bf16* __restrict__ B,
             const float* __restrict__ bias, OUTT* __restrict__ C,
             int M, int N, int K, long sA, long sB, long sC, int zc)
{
    __shared__ __align__(16) bf16 sh[2 * 16384];
    const int gx = gridDim.x, gy = gridDim.y;
    int flat = xcd_flat((blockIdx.z * gy + blockIdx.y) * gx + blockIdx.x,
                        gx * gy * gridDim.z);
    const int bx = flat % gx;
    const int tmp = flat / gx;
    const int by = tmp % gy;
    const int bz = tmp / gy;
    bt_body<EPI, HAS_BIAS, OUTT>(sh, A + (long)bz * sA, B + (long)bz * sB, bias,
                                 C + (long)bz * sC, N, K, by * 128, bx * 128, zc);
}

// ---- dual-GEMM kernel: two independent bias-free GEMMs in ONE dispatch ----
// Blocks [0, nblk1) run GEMM-1 (grid gx1 x gy1 x gz1), the rest GEMM-2.
// Motivation: pk (384 blocks, 0.75 fill-rounds) and qv (1152, 2.25 ragged
// rounds) are data-independent; merged = 1536 blocks = 3.0 clean rounds at
// 2 blocks/CU x 256 CUs, one launch instead of two.
template<int EPIa, typename OUTa, int EPIb, typename OUTb>
__global__ __launch_bounds__(256, 2)
void gemm_dual(const bf16* __restrict__ A1, const bf16* __restrict__ B1,
               OUTa* __restrict__ C1, int N1, int K1,
               long sA1, long sB1, long sC1, int zc1, int gx1, int gy1, int nblk1,
               const bf16* __restrict__ A2, const bf16* __restrict__ B2,
               OUTb* __restrict__ C2, int N2, int K2,
               long sA2, long sB2, long sC2, int zc2, int gx2, int gy2)
{
    __shared__ __align__(16) bf16 sh[2 * 16384];
    int flat = xcd_flat(blockIdx.x, gridDim.x);
    if (flat < nblk1) {
        const int bx = flat % gx1;
        const int tmp = flat / gx1;
        const int by = tmp % gy1;
        const int bz = tmp / gy1;
        bt_body<EPIa, false, OUTa>(sh, A1 + (long)bz * sA1, B1 + (long)bz * sB1,
                                   nullptr, C1 + (long)bz * sC1,
                                   N1, K1, by * 128, bx * 128, zc1);
    } else {
        flat -= nblk1;
        const int bx = flat % gx2;
        const int tmp = flat / gx2;
        const int by = tmp % gy2;
        const int bz = tmp / gy2;
        bt_body<EPIb, false, OUTb>(sh, A2 + (long)bz * sA2, B2 + (long)bz * sB2,
                                   nullptr, C2 + (long)bz * sC2,
                                   N2, K2, by * 128, bx * 128, zc2);
    }
}

// ---------------- LayerNorm over C=768 per row ----------------
template<typename OUTT>
__global__ __launch_bounds__(256)
void ln_rows(const float* __restrict__ x, OUTT* __restrict__ y,
             const float* __restrict__ g, const float* __restrict__ bta)
{
    int r = blockIdx.x;
    const float* xr = x + (long)r * Cdim;
    OUTT* yr = y + (long)r * Cdim;
    int t = threadIdx.x;

    float v0 = xr[t], v1 = xr[t + 256], v2 = xr[t + 512];
    float s  = v0 + v1 + v2;
    float s2 = v0 * v0 + v1 * v1 + v2 * v2;
    #pragma unroll
    for (int o = 32; o > 0; o >>= 1) {
        s  += __shfl_down(s,  o, 64);
        s2 += __shfl_down(s2, o, 64);
    }
    __shared__ float sh[4], sh2[4];
    int wid = t >> 6;
    if ((t & 63) == 0) { sh[wid] = s; sh2[wid] = s2; }
    __syncthreads();
    float S  = sh[0] + sh[1] + sh[2] + sh[3];
    float S2 = sh2[0] + sh2[1] + sh2[2] + sh2[3];
    float mu  = S * (1.f / Cdim);
    float var = S2 * (1.f / Cdim) - mu * mu;
    float inv = rsqrtf(var + 1e-5f);
    stv(&yr[t],       (v0 - mu) * inv * g[t]       + bta[t]);
    stv(&yr[t + 256], (v1 - mu) * inv * g[t + 256] + bta[t + 256]);
    stv(&yr[t + 512], (v2 - mu) * inv * g[t + 512] + bta[t + 512]);
}

// ---------------- fp32 -> bf16 cast (8 elems/thread) ----------------
__global__ void cast_f2b(const float* __restrict__ in, bf16* __restrict__ out, long n)
{
    long i = ((long)blockIdx.x * 256 + threadIdx.x) * 8;
    if (i >= n) return;
    float4 v0 = *(const float4*)(in + i);
    float4 v1 = *(const float4*)(in + i + 4);
    union { bf16 b[8]; uint4 u; } t;
    t.b[0] = __float2bfloat16(v0.x); t.b[1] = __float2bfloat16(v0.y);
    t.b[2] = __float2bfloat16(v0.z); t.b[3] = __float2bfloat16(v0.w);
    t.b[4] = __float2bfloat16(v1.x); t.b[5] = __float2bfloat16(v1.y);
    t.b[6] = __float2bfloat16(v1.z); t.b[7] = __float2bfloat16(v1.w);
    *(uint4*)(out + i) = t.u;
}

// interleaved cast: dst layout per layer l = [Wq(l) CC][Wv(l) CC]
#define CCn (768*768)
__global__ void cast_qv(const float* __restrict__ Wq, const float* __restrict__ Wv,
                        bf16* __restrict__ dst)
{
    long i = ((long)blockIdx.x * 256 + threadIdx.x) * 8;
    if (i >= (long)Ldim * 2 * CCn) return;
    long l = i / (2 * CCn); long rem = i - l * 2 * CCn;
    const float* src = (rem < CCn) ? (Wq + l * CCn + rem) : (Wv + l * CCn + rem - CCn);
    float4 v0 = *(const float4*)(src);
    float4 v1 = *(const float4*)(src + 4);
    union { bf16 b[8]; uint4 u; } t;
    t.b[0] = __float2bfloat16(v0.x); t.b[1] = __float2bfloat16(v0.y);
    t.b[2] = __float2bfloat16(v0.z); t.b[3] = __float2bfloat16(v0.w);
    t.b[4] = __float2bfloat16(v1.x); t.b[5] = __float2bfloat16(v1.y);
    t.b[6] = __float2bfloat16(v1.z); t.b[7] = __float2bfloat16(v1.w);
    *(uint4*)(dst + i) = t.u;
}

// ---------------- im2col (bf16 out) for stride-16 patch conv ----------------
__global__ void im2col_patch(const float* __restrict__ x, bf16* __restrict__ out)
{
    long idx = (long)blockIdx.x * 256 + threadIdx.x;
    if (idx >= (long)PROWS * Cdim) return;
    int col = (int)(idx % Cdim);
    int row = (int)(idx / Cdim);
    int c = col >> 8, rem = col & 255, k = rem >> 4, l = rem & 15;
    int wp = row % 14; int t2 = row / 14; int hp = t2 % 14; int b = t2 / 14;
    out[idx] = __float2bfloat16(x[(((long)b * 3 + c) * 224 + hp * 16 + k) * 224 + wp * 16 + l]);
}

// h[b*256+n, c]: n<210 -> token value + pos_enc; n>=210 -> 0
__global__ void assemble_h(const float* __restrict__ pel,
                           const float* __restrict__ cls_tok,
                           const float* __restrict__ pos_enc,
                           float* __restrict__ h)
{
    long idx = (long)blockIdx.x * 256 + threadIdx.x;
    if (idx >= (long)TPAD * Cdim) return;
    int c = (int)(idx % Cdim);
    long t = idx / Cdim;
    int n = (int)(t % NTOKP); int b = (int)(t / NTOKP);
    if (n >= NTOK) { h[idx] = 0.f; return; }
    int hp = n / 15, w = n % 15;
    float pos = pos_enc[(long)c * NTOK + hp * 15 + w];
    float v = (w == 0) ? cls_tok[c]
                       : pel[((long)b * NPATCH + hp * 14 + (w - 1)) * Cdim + c];
    h[idx] = v + pos;
}

// cls_feat[b,c] = mean_hp h[b*256 + hp*15, c]
__global__ void cls_pool(const float* __restrict__ h, float* __restrict__ cf)
{
    int idx = blockIdx.x * 256 + threadIdx.x;
    if (idx >= Bsz * Cdim) return;
    int c = idx % Cdim, b = idx / Cdim;
    float s = 0.f;
    #pragma unroll
    for (int hp = 0; hp < 14; ++hp)
        s += h[((long)b * NTOKP + hp * 15) * Cdim + c];
    cf[idx] = s * (1.f / 14.f);
}

__global__ void head_gemm(const float* __restrict__ cf, const float* __restrict__ w,
                          const float* __restrict__ bias, float* __restrict__ out)
{
    int idx = blockIdx.x * 256 + threadIdx.x;
    if (idx >= Bsz * NCls) return;
    int j = idx % NCls, b = idx / NCls;
    const float* cr = cf + (long)b * Cdim;
    const float* wr = w + (long)j * Cdim;
    float s = 0.f;
    for (int c = 0; c < Cdim; ++c) s += cr[c] * wr[c];
    out[idx] = s + bias[j];
}

// -------------------------------------------------------------------------
extern "C" void kernel_launch(void* const* d_in, const int* in_sizes, int n_in,
                              void* d_out, int out_size, void* d_ws, size_t ws_size,
                              hipStream_t stream)
{
    const float* x       = (const float*)d_in[0];
    const float* patch_w = (const float*)d_in[1];
    const float* patch_b = (const float*)d_in[2];
    const float* pe_g    = (const float*)d_in[3];
    const float* pe_b    = (const float*)d_in[4];
    const float* cls_tok = (const float*)d_in[5];
    const float* pos_enc = (const float*)d_in[6];
    const float* Wq      = (const float*)d_in[7];
    const float* Wk      = (const float*)d_in[8];
    const float* Wv      = (const float*)d_in[9];
    const float* Wo_w    = (const float*)d_in[10];
    const float* Wo_b    = (const float*)d_in[11];
    const float* ln1_g   = (const float*)d_in[12];
    const float* ln1_b   = (const float*)d_in[13];
    const float* ln2_g   = (const float*)d_in[14];
    const float* ln2_b   = (const float*)d_in[15];
    const float* mlp1_w  = (const float*)d_in[16];
    const float* mlp1_b  = (const float*)d_in[17];
    const float* mlp2_w  = (const float*)d_in[18];
    const float* mlp2_b  = (const float*)d_in[19];
    const float* head_w  = (const float*)d_in[20];
    const float* head_b  = (const float*)d_in[21];

    // ---------------- workspace layout (R7 padded token layout) ----------------
    char* base = (char*)d_ws;
    size_t off = 0;
    auto take = [&](size_t bytes) -> char* {
        char* p = base + off; off += (bytes + 255) & ~(size_t)255; return p;
    };
    float* h    = (float*)take((size_t)TPAD * Cdim * 4);           // fp32 residual
    bf16*  xn   = (bf16*) take((size_t)TPAD * Cdim * 2);
    bf16*  pk   = (bf16*) take((size_t)TPAD * Cdim * 2);
    bf16*  pqvT = (bf16*) take((size_t)Bsz * 1536 * NTOKP * 2);    // [B][q,v][256]
    char*  big  = take((size_t)TPAD * Mdim * 2);                   // 50.3 MB shared region
    bf16*  wbf  = (bf16*) take((size_t)85524480 * 2);              // bf16 weights
    if (off > ws_size) return;

    // big-region aliases (phase-disjoint)
    bf16*  hid = (bf16*)big;                                       // MLP phase
    bf16*  qv  = (bf16*)big;                                       // attn phase [B][768][768]
    bf16*  att = (bf16*)(big + (size_t)Bsz * Cdim * Cdim * 2);     // attn phase
    bf16*  im  = (bf16*)big;                                       // patch phase
    float* peo = (float*)(big + 9633792);
    float* pel = (float*)(big + 9633792 + 19267584);
    float* cf  = (float*)big;                                      // head phase

    // bf16 weight sub-buffers
    const long CC  = (long)Cdim * Cdim;             // 589,824
    const long nCC = (long)Ldim * CC;               // 7,077,888
    const long nMC = (long)Ldim * Mdim * Cdim;      // 28,311,552
    bf16* wqv_bf = wbf;                 // interleaved per layer: [wq CC][wv CC]
    bf16* wk_bf  = wqv_bf + 2 * nCC;
    bf16* wo_bf  = wk_bf + nCC;
    bf16* m1_bf  = wo_bf + nCC;
    bf16* m2_bf  = m1_bf + nMC;
    bf16* pw_bf  = m2_bf + nMC;

    auto cast = [&](const float* src, bf16* dst, long n) {
        cast_f2b<<<dim3((unsigned)((n / 8 + 255) / 256)), 256, 0, stream>>>(src, dst, n);
    };
    cast_qv<<<dim3((unsigned)((2 * nCC / 8 + 255) / 256)), 256, 0, stream>>>(Wq, Wv, wqv_bf);
    cast(Wk, wk_bf, nCC);
    cast(Wo_w, wo_bf, nCC); cast(mlp1_w, m1_bf, nMC); cast(mlp2_w, m2_bf, nMC);
    cast(patch_w, pw_bf, CC);

    // ---------------- patch embedding ----------------
    {
        long tot = (long)PROWS * Cdim;
        im2col_patch<<<dim3((unsigned)((tot + 255) / 256)), 256, 0, stream>>>(x, im);
        gemm_bt<EPI_NONE, true, float><<<dim3(6, 49, 1), 256, 0, stream>>>(
            im, pw_bf, patch_b, peo, PROWS, Cdim, Cdim, 0, 0, 0, 0);
        ln_rows<float><<<dim3(PROWS), 256, 0, stream>>>(peo, pel, pe_g, pe_b);
        long tot2 = (long)TPAD * Cdim;
        assemble_h<<<dim3((unsigned)((tot2 + 255) / 256)), 256, 0, stream>>>(
            pel, cls_tok, pos_enc, h);
    }

    // ---------------- transformer layers ----------------
    const long TNC = (long)NTOKP * Cdim;            // 196,608 per-batch activation stride
    const long QVS = (long)1536 * NTOKP;            // 393,216 per-batch pqvT stride
    for (int l = 0; l < Ldim; ++l) {
        const bf16*  wqv = wqv_bf + (long)l * 2 * CC;
        const bf16*  wk  = wk_bf + (long)l * CC;
        const bf16*  wo  = wo_bf + (long)l * CC;
        const bf16*  m1  = m1_bf + (long)l * Mdim * Cdim;
        const bf16*  m2  = m2_bf + (long)l * Mdim * Cdim;
        const float* wob = Wo_b  + (long)l * Cdim;
        const float* g1  = ln1_g + (long)l * Cdim;
        const float* b1  = ln1_b + (long)l * Cdim;
        const float* g2  = ln2_g + (long)l * Cdim;
        const float* b2  = ln2_b + (long)l * Cdim;
        const float* m1b = mlp1_b + (long)l * Mdim;
        const float* m2b = mlp2_b + (long)l * Cdim;

        ln_rows<bf16><<<dim3(TPAD), 256, 0, stream>>>(h, xn, g1, b1);

        // pqvT[b][c(0..1535)][n] = phi(sum_k wqv[c,k]*xn[b,n,k]); pad cols zeroed
        gemm_bt<EPI_PHI, false, bf16><<<dim3(2, 12, Bsz), 256, 0, stream>>>(
            wqv, xn, nullptr, pqvT, 1536, NTOKP, Cdim, 0, TNC, QVS, NTOK);

        // FUSED dispatch: pk (384 blocks) + qv (1152 blocks) = 1536 = 3.0 rounds
        //   pk[t][d]   = phi(sum_k xn[t,k]*wk[d,k])             [needs xn]
        //   qv[b][c][d]= sum_n pqT[b,c,n]*pvT[b,d,n]            [needs pqvT]
        gemm_dual<EPI_PHI, bf16, EPI_NONE, bf16><<<dim3(384 + 1152), 256, 0, stream>>>(
            xn, wk, pk, Cdim, Cdim, 0, 0, 0, 1 << 30, 6, TPAD / 128, 384,
            pqvT, pqvT + (long)768 * NTOKP, qv, Cdim, NTOKP, QVS, QVS, CC, 0, 6, 6);

        // att[b][n][c] = sum_d pk[b,n,d]*qv[b,c,d]
        gemm_bt<EPI_NONE, false, bf16><<<dim3(6, 2, Bsz), 256, 0, stream>>>(
            pk, qv, nullptr, att, NTOKP, Cdim, Cdim, TNC, CC, TNC, 0);
        // h += att @ wo^T + wob
        gemm_bt<EPI_RESID, true, float><<<dim3(6, TPAD / 128, 1), 256, 0, stream>>>(
            att, wo, wob, h, TPAD, Cdim, Cdim, 0, 0, 0, 0);

        ln_rows<bf16><<<dim3(TPAD), 256, 0, stream>>>(h, xn, g2, b2);

        // hid = gelu(xn @ m1^T + m1b)
        gemm_bt<EPI_GELU, true, bf16><<<dim3(Mdim / 128, TPAD / 128, 1), 256, 0, stream>>>(
            xn, m1, m1b, hid, TPAD, Mdim, Cdim, 0, 0, 0, 0);
        // h += hid @ m2^T + m2b
        gemm_bt<EPI_RESID, true, float><<<dim3(6, TPAD / 128, 1), 256, 0, stream>>>(
            hid, m2, m2b, h, TPAD, Cdim, Mdim, 0, 0, 0, 0);
    }

    // ---------------- head ----------------
    cls_pool<<<dim3((Bsz * Cdim + 255) / 256), 256, 0, stream>>>(h, cf);
    head_gemm<<<dim3((Bsz * NCls + 255) / 256), 256, 0, stream>>>(
        cf, head_w, head_b, (float*)d_out);
}

// Round 17
// 3090.579 us; speedup vs baseline: 1.0664x; 1.0664x over previous
//
#include <hip/hip_runtime.h>
#include <hip/hip_bf16.h>
#include <math.h>

// ---------------- model dims ----------------
#define Bsz 32
#define Cdim 768
#define Mdim 3072
#define Ldim 12
#define NTOK 210            // real tokens per image: 14*(14+1)
#define NTOKP 256           // padded tokens per image
#define TPAD (Bsz*NTOKP)    // 8192 padded token rows
#define NPATCH 196
#define PROWS (Bsz*NPATCH)  // 6272 = 49*128
#define NCls 1000

typedef __hip_bfloat16 bf16;
typedef __attribute__((ext_vector_type(8))) short bfrag;   // 8 bf16 = 4 VGPR
typedef __attribute__((ext_vector_type(4))) float f32x4;

enum { EPI_NONE = 0, EPI_PHI = 1, EPI_GELU = 2, EPI_RESID = 3 };

__device__ __forceinline__ void gl_lds16(const void* g, void* l) {
    __builtin_amdgcn_global_load_lds(
        (const __attribute__((address_space(1))) unsigned*)g,
        (__attribute__((address_space(3))) unsigned*)l, 16, 0, 0);
}

__device__ __forceinline__ void stv(float* p, float v) { *p = v; }
__device__ __forceinline__ void stv(bf16* p, float v)  { *p = __float2bfloat16(v); }

// ---- XCD-aware bijective swizzle (T1/m204) ----
__device__ __forceinline__ void xcd_swizzle(int& bx, int& by, int& bz)
{
    const int gx = gridDim.x, gy = gridDim.y;
    const int nwg = gx * gy * gridDim.z;
    int flat = (blockIdx.z * gy + blockIdx.y) * gx + blockIdx.x;
    int q8 = nwg >> 3, r8 = nwg & 7;
    int xcd = flat & 7, loc = flat >> 3;
    flat = ((xcd < r8) ? xcd * (q8 + 1) : r8 * (q8 + 1) + (xcd - r8) * q8) + loc;
    bx = flat % gx;
    int tmp = flat / gx;
    by = tmp % gy;
    bz = tmp / gy;
}

// -------------------------------------------------------------------------
// MFMA NT-GEMM, 128x128 tile, BK=64, 2-slot dbuf (64KB LDS), counted
// vmcnt(8) — the R7 configuration, measured best (3092us total) across
// 16 rounds of axis exploration (schedule depth, tile shape, BK,
// occupancy, MFMA shape, packing, fusion: all null or negative).
// T2 chunk-XOR LDS swizzle (0 conflicts), T1 XCD swizzle, T5 setprio.
// C[m,n] = sum_k A[m,k]*B[n,k] (+bias) + epilogue. Batched via blockIdx.z.
// M%128==0, N%128==0, K%64==0 guaranteed by caller.
// zc: EPI_PHI only — output cols gn>=zc written as 0 (token-pad cols).
// -------------------------------------------------------------------------
template<int EPI, bool HAS_BIAS, typename OUTT>
__global__ __launch_bounds__(256, 2)
void gemm_bt(const bf16* __restrict__ A, const bf16* __restrict__ B,
             const float* __restrict__ bias, OUTT* __restrict__ C,
             int M, int N, int K, long sA, long sB, long sC, int zc)
{
    int bx, by, bz;
    xcd_swizzle(bx, by, bz);

    A += (long)bz * sA; B += (long)bz * sB; C += (long)bz * sC;
    const int m0 = by * 128, n0 = bx * 128;

    __shared__ __align__(16) bf16 sh[2 * 16384];

    const int tid  = threadIdx.x;
    const int lane = tid & 63, wid = tid >> 6;
    const int wr = wid >> 1, wc = wid & 1;
    const int lr = lane & 15, lg = lane >> 4;

    f32x4 acc[4][4];
    #pragma unroll
    for (int i = 0; i < 4; ++i)
        #pragma unroll
        for (int j = 0; j < 4; ++j)
            acc[i][j] = f32x4{0.f, 0.f, 0.f, 0.f};

    // staging: linear LDS dest; inverse-swizzled GLOBAL 16B chunk (rule 21)
    const int srow = tid >> 3;                                   // 0..31
    const int scol = ((tid & 7) ^ ((tid >> 3) & 7)) * 8;         // elems
    const bf16* gA = A + (long)(m0 + srow) * K + scol;
    const bf16* gB = B + (long)(n0 + srow) * K + scol;

    auto stage = [&](int slot) {
        bf16* s = sh + slot * 16384;
        #pragma unroll
        for (int L = 0; L < 4; ++L)
            gl_lds16(gA + (long)(L * 32) * K, s + L * 2048 + tid * 8);
        #pragma unroll
        for (int L = 0; L < 4; ++L)
            gl_lds16(gB + (long)(L * 32) * K, s + 8192 + L * 2048 + tid * 8);
        gA += 64; gB += 64;
    };

    // fragment reads: phys 16B-chunk = logical ^ (row&7)
    const int rxor = lr & 7;
    const int arow = (wr * 64 + lr) * 64;
    const int brow = (wc * 64 + lr) * 64;

    const int kt = K >> 6;
    stage(0);

    for (int t = 0; t < kt; ++t) {
        if (t + 1 < kt) {
            stage((t + 1) & 1);
            asm volatile("s_waitcnt vmcnt(8)" ::: "memory");   // tile t landed
        } else {
            asm volatile("s_waitcnt vmcnt(0)" ::: "memory");
        }
        __builtin_amdgcn_s_barrier();

        const bf16* Ab = sh + (t & 1) * 16384;
        const bf16* Bb = Ab + 8192;
        bfrag a[4][2], b[4][2];
        #pragma unroll
        for (int i = 0; i < 4; ++i)
            #pragma unroll
            for (int ks = 0; ks < 2; ++ks)
                a[i][ks] = *(const bfrag*)(Ab + arow + i * 1024 + ((ks * 4 + lg) ^ rxor) * 8);
        #pragma unroll
        for (int j = 0; j < 4; ++j)
            #pragma unroll
            for (int ks = 0; ks < 2; ++ks)
                b[j][ks] = *(const bfrag*)(Bb + brow + j * 1024 + ((ks * 4 + lg) ^ rxor) * 8);

        __builtin_amdgcn_s_setprio(1);
        #pragma unroll
        for (int ks = 0; ks < 2; ++ks)
            #pragma unroll
            for (int i = 0; i < 4; ++i)
                #pragma unroll
                for (int j = 0; j < 4; ++j)
                    acc[i][j] = __builtin_amdgcn_mfma_f32_16x16x32_bf16(a[i][ks], b[j][ks], acc[i][j], 0, 0, 0);
        __builtin_amdgcn_s_setprio(0);
        __builtin_amdgcn_s_barrier();
    }

    // epilogue: C/D mapping col=lane&15, row=(lane>>4)*4+reg  [m89/m91]
    const int cidx  = lane & 15;
    const int rbase = (lane >> 4) * 4;
    #pragma unroll
    for (int i = 0; i < 4; ++i) {
        #pragma unroll
        for (int j = 0; j < 4; ++j) {
            const int gn = n0 + wc * 64 + j * 16 + cidx;
            float bv = HAS_BIAS ? bias[gn] : 0.f;
            #pragma unroll
            for (int r = 0; r < 4; ++r) {
                const int gm = m0 + wr * 64 + i * 16 + rbase + r;
                float v = acc[i][j][r] + bv;
                long idx = (long)gm * N + gn;
                if (EPI == EPI_PHI) {
                    v = (v > 0.f) ? (v + 1.f) : expf(v);
                    if (gn >= zc) v = 0.f;           // zero token-pad cols
                }
                if (EPI == EPI_GELU)  v = 0.5f * v * (1.f + erff(v * 0.70710678118654752f));
                if (EPI == EPI_RESID) v += ((const float*)C)[idx];
                stv(&C[idx], v);
            }
        }
    }
}

// ---------------- LayerNorm over C=768 per row ----------------
template<typename OUTT>
__global__ __launch_bounds__(256)
void ln_rows(const float* __restrict__ x, OUTT* __restrict__ y,
             const float* __restrict__ g, const float* __restrict__ bta)
{
    int r = blockIdx.x;
    const float* xr = x + (long)r * Cdim;
    OUTT* yr = y + (long)r * Cdim;
    int t = threadIdx.x;

    float v0 = xr[t], v1 = xr[t + 256], v2 = xr[t + 512];
    float s  = v0 + v1 + v2;
    float s2 = v0 * v0 + v1 * v1 + v2 * v2;
    #pragma unroll
    for (int o = 32; o > 0; o >>= 1) {
        s  += __shfl_down(s,  o, 64);
        s2 += __shfl_down(s2, o, 64);
    }
    __shared__ float sh[4], sh2[4];
    int wid = t >> 6;
    if ((t & 63) == 0) { sh[wid] = s; sh2[wid] = s2; }
    __syncthreads();
    float S  = sh[0] + sh[1] + sh[2] + sh[3];
    float S2 = sh2[0] + sh2[1] + sh2[2] + sh2[3];
    float mu  = S * (1.f / Cdim);
    float var = S2 * (1.f / Cdim) - mu * mu;
    float inv = rsqrtf(var + 1e-5f);
    stv(&yr[t],       (v0 - mu) * inv * g[t]       + bta[t]);
    stv(&yr[t + 256], (v1 - mu) * inv * g[t + 256] + bta[t + 256]);
    stv(&yr[t + 512], (v2 - mu) * inv * g[t + 512] + bta[t + 512]);
}

// ---------------- fp32 -> bf16 cast (8 elems/thread) ----------------
__global__ void cast_f2b(const float* __restrict__ in, bf16* __restrict__ out, long n)
{
    long i = ((long)blockIdx.x * 256 + threadIdx.x) * 8;
    if (i >= n) return;
    float4 v0 = *(const float4*)(in + i);
    float4 v1 = *(const float4*)(in + i + 4);
    union { bf16 b[8]; uint4 u; } t;
    t.b[0] = __float2bfloat16(v0.x); t.b[1] = __float2bfloat16(v0.y);
    t.b[2] = __float2bfloat16(v0.z); t.b[3] = __float2bfloat16(v0.w);
    t.b[4] = __float2bfloat16(v1.x); t.b[5] = __float2bfloat16(v1.y);
    t.b[6] = __float2bfloat16(v1.z); t.b[7] = __float2bfloat16(v1.w);
    *(uint4*)(out + i) = t.u;
}

// interleaved cast: dst layout per layer l = [Wq(l) CC][Wv(l) CC]
#define CCn (768*768)
__global__ void cast_qv(const float* __restrict__ Wq, const float* __restrict__ Wv,
                        bf16* __restrict__ dst)
{
    long i = ((long)blockIdx.x * 256 + threadIdx.x) * 8;
    if (i >= (long)Ldim * 2 * CCn) return;
    long l = i / (2 * CCn); long rem = i - l * 2 * CCn;
    const float* src = (rem < CCn) ? (Wq + l * CCn + rem) : (Wv + l * CCn + rem - CCn);
    float4 v0 = *(const float4*)(src);
    float4 v1 = *(const float4*)(src + 4);
    union { bf16 b[8]; uint4 u; } t;
    t.b[0] = __float2bfloat16(v0.x); t.b[1] = __float2bfloat16(v0.y);
    t.b[2] = __float2bfloat16(v0.z); t.b[3] = __float2bfloat16(v0.w);
    t.b[4] = __float2bfloat16(v1.x); t.b[5] = __float2bfloat16(v1.y);
    t.b[6] = __float2bfloat16(v1.z); t.b[7] = __float2bfloat16(v1.w);
    *(uint4*)(dst + i) = t.u;
}

// ---------------- im2col (bf16 out) for stride-16 patch conv ----------------
__global__ void im2col_patch(const float* __restrict__ x, bf16* __restrict__ out)
{
    long idx = (long)blockIdx.x * 256 + threadIdx.x;
    if (idx >= (long)PROWS * Cdim) return;
    int col = (int)(idx % Cdim);
    int row = (int)(idx / Cdim);
    int c = col >> 8, rem = col & 255, k = rem >> 4, l = rem & 15;
    int wp = row % 14; int t2 = row / 14; int hp = t2 % 14; int b = t2 / 14;
    out[idx] = __float2bfloat16(x[(((long)b * 3 + c) * 224 + hp * 16 + k) * 224 + wp * 16 + l]);
}

// h[b*256+n, c]: n<210 -> token value + pos_enc; n>=210 -> 0
__global__ void assemble_h(const float* __restrict__ pel,
                           const float* __restrict__ cls_tok,
                           const float* __restrict__ pos_enc,
                           float* __restrict__ h)
{
    long idx = (long)blockIdx.x * 256 + threadIdx.x;
    if (idx >= (long)TPAD * Cdim) return;
    int c = (int)(idx % Cdim);
    long t = idx / Cdim;
    int n = (int)(t % NTOKP); int b = (int)(t / NTOKP);
    if (n >= NTOK) { h[idx] = 0.f; return; }
    int hp = n / 15, w = n % 15;
    float pos = pos_enc[(long)c * NTOK + hp * 15 + w];
    float v = (w == 0) ? cls_tok[c]
                       : pel[((long)b * NPATCH + hp * 14 + (w - 1)) * Cdim + c];
    h[idx] = v + pos;
}

// cls_feat[b,c] = mean_hp h[b*256 + hp*15, c]
__global__ void cls_pool(const float* __restrict__ h, float* __restrict__ cf)
{
    int idx = blockIdx.x * 256 + threadIdx.x;
    if (idx >= Bsz * Cdim) return;
    int c = idx % Cdim, b = idx / Cdim;
    float s = 0.f;
    #pragma unroll
    for (int hp = 0; hp < 14; ++hp)
        s += h[((long)b * NTOKP + hp * 15) * Cdim + c];
    cf[idx] = s * (1.f / 14.f);
}

__global__ void head_gemm(const float* __restrict__ cf, const float* __restrict__ w,
                          const float* __restrict__ bias, float* __restrict__ out)
{
    int idx = blockIdx.x * 256 + threadIdx.x;
    if (idx >= Bsz * NCls) return;
    int j = idx % NCls, b = idx / NCls;
    const float* cr = cf + (long)b * Cdim;
    const float* wr = w + (long)j * Cdim;
    float s = 0.f;
    for (int c = 0; c < Cdim; ++c) s += cr[c] * wr[c];
    out[idx] = s + bias[j];
}

// -------------------------------------------------------------------------
extern "C" void kernel_launch(void* const* d_in, const int* in_sizes, int n_in,
                              void* d_out, int out_size, void* d_ws, size_t ws_size,
                              hipStream_t stream)
{
    const float* x       = (const float*)d_in[0];
    const float* patch_w = (const float*)d_in[1];
    const float* patch_b = (const float*)d_in[2];
    const float* pe_g    = (const float*)d_in[3];
    const float* pe_b    = (const float*)d_in[4];
    const float* cls_tok = (const float*)d_in[5];
    const float* pos_enc = (const float*)d_in[6];
    const float* Wq      = (const float*)d_in[7];
    const float* Wk      = (const float*)d_in[8];
    const float* Wv      = (const float*)d_in[9];
    const float* Wo_w    = (const float*)d_in[10];
    const float* Wo_b    = (const float*)d_in[11];
    const float* ln1_g   = (const float*)d_in[12];
    const float* ln1_b   = (const float*)d_in[13];
    const float* ln2_g   = (const float*)d_in[14];
    const float* ln2_b   = (const float*)d_in[15];
    const float* mlp1_w  = (const float*)d_in[16];
    const float* mlp1_b  = (const float*)d_in[17];
    const float* mlp2_w  = (const float*)d_in[18];
    const float* mlp2_b  = (const float*)d_in[19];
    const float* head_w  = (const float*)d_in[20];
    const float* head_b  = (const float*)d_in[21];

    // ---------------- workspace layout ----------------
    char* base = (char*)d_ws;
    size_t off = 0;
    auto take = [&](size_t bytes) -> char* {
        char* p = base + off; off += (bytes + 255) & ~(size_t)255; return p;
    };
    float* h    = (float*)take((size_t)TPAD * Cdim * 4);           // fp32 residual
    bf16*  xn   = (bf16*) take((size_t)TPAD * Cdim * 2);
    bf16*  pk   = (bf16*) take((size_t)TPAD * Cdim * 2);
    bf16*  pqvT = (bf16*) take((size_t)Bsz * 1536 * NTOKP * 2);    // [B][q0..767,v768..1535][256]
    char*  big  = take((size_t)TPAD * Mdim * 2);                   // 50.3 MB shared region
    bf16*  wbf  = (bf16*) take((size_t)85524480 * 2);              // bf16 weights
    if (off > ws_size) return;

    // big-region aliases (phase-disjoint)
    bf16*  hid = (bf16*)big;                                       // MLP phase
    bf16*  qv  = (bf16*)big;                                       // attn phase [B][768][768]
    bf16*  att = (bf16*)(big + (size_t)Bsz * Cdim * Cdim * 2);     // attn phase
    bf16*  im  = (bf16*)big;                                       // patch phase
    float* peo = (float*)(big + 9633792);
    float* pel = (float*)(big + 9633792 + 19267584);
    float* cf  = (float*)big;                                      // head phase

    // bf16 weight sub-buffers
    const long CC  = (long)Cdim * Cdim;             // 589,824
    const long nCC = (long)Ldim * CC;               // 7,077,888
    const long nMC = (long)Ldim * Mdim * Cdim;      // 28,311,552
    bf16* wqv_bf = wbf;                 // interleaved per layer: [wq CC][wv CC]
    bf16* wk_bf  = wqv_bf + 2 * nCC;
    bf16* wo_bf  = wk_bf + nCC;
    bf16* m1_bf  = wo_bf + nCC;
    bf16* m2_bf  = m1_bf + nMC;
    bf16* pw_bf  = m2_bf + nMC;

    auto cast = [&](const float* src, bf16* dst, long n) {
        cast_f2b<<<dim3((unsigned)((n / 8 + 255) / 256)), 256, 0, stream>>>(src, dst, n);
    };
    cast_qv<<<dim3((unsigned)((2 * nCC / 8 + 255) / 256)), 256, 0, stream>>>(Wq, Wv, wqv_bf);
    cast(Wk, wk_bf, nCC);
    cast(Wo_w, wo_bf, nCC); cast(mlp1_w, m1_bf, nMC); cast(mlp2_w, m2_bf, nMC);
    cast(patch_w, pw_bf, CC);

    // ---------------- patch embedding ----------------
    {
        long tot = (long)PROWS * Cdim;
        im2col_patch<<<dim3((unsigned)((tot + 255) / 256)), 256, 0, stream>>>(x, im);
        gemm_bt<EPI_NONE, true, float><<<dim3(6, 49, 1), 256, 0, stream>>>(
            im, pw_bf, patch_b, peo, PROWS, Cdim, Cdim, 0, 0, 0, 0);
        ln_rows<float><<<dim3(PROWS), 256, 0, stream>>>(peo, pel, pe_g, pe_b);
        long tot2 = (long)TPAD * Cdim;
        assemble_h<<<dim3((unsigned)((tot2 + 255) / 256)), 256, 0, stream>>>(
            pel, cls_tok, pos_enc, h);
    }

    // ---------------- transformer layers ----------------
    const long TNC = (long)NTOKP * Cdim;            // 196,608 per-batch activation stride
    const long QVS = (long)1536 * NTOKP;            // 393,216 per-batch pqvT stride
    for (int l = 0; l < Ldim; ++l) {
        const bf16*  wqv = wqv_bf + (long)l * 2 * CC;
        const bf16*  wk  = wk_bf + (long)l * CC;
        const bf16*  wo  = wo_bf + (long)l * CC;
        const bf16*  m1  = m1_bf + (long)l * Mdim * Cdim;
        const bf16*  m2  = m2_bf + (long)l * Mdim * Cdim;
        const float* wob = Wo_b  + (long)l * Cdim;
        const float* g1  = ln1_g + (long)l * Cdim;
        const float* b1  = ln1_b + (long)l * Cdim;
        const float* g2  = ln2_g + (long)l * Cdim;
        const float* b2  = ln2_b + (long)l * Cdim;
        const float* m1b = mlp1_b + (long)l * Mdim;
        const float* m2b = mlp2_b + (long)l * Cdim;

        ln_rows<bf16><<<dim3(TPAD), 256, 0, stream>>>(h, xn, g1, b1);

        // pqvT[b][c(0..1535)][n] = phi(sum_k wqv[c,k]*xn[b,n,k]); pad cols zeroed
        gemm_bt<EPI_PHI, false, bf16><<<dim3(2, 12, Bsz), 256, 0, stream>>>(
            wqv, xn, nullptr, pqvT, 1536, NTOKP, Cdim, 0, TNC, QVS, NTOK);
        // pk[t][d] = phi(sum_k xn[t,k]*wk[d,k])
        gemm_bt<EPI_PHI, false, bf16><<<dim3(6, TPAD / 128, 1), 256, 0, stream>>>(
            xn, wk, nullptr, pk, TPAD, Cdim, Cdim, 0, 0, 0, 1 << 30);

        // qv[b][c][d] = sum_n pqT[b,c,n]*pvT[b,d,n]
        gemm_bt<EPI_NONE, false, bf16><<<dim3(6, 6, Bsz), 256, 0, stream>>>(
            pqvT, pqvT + (long)768 * NTOKP, nullptr, qv, Cdim, Cdim, NTOKP,
            QVS, QVS, CC, 0);
        // att[b][n][c] = sum_d pk[b,n,d]*qv[b,c,d]
        gemm_bt<EPI_NONE, false, bf16><<<dim3(6, 2, Bsz), 256, 0, stream>>>(
            pk, qv, nullptr, att, NTOKP, Cdim, Cdim, TNC, CC, TNC, 0);
        // h += att @ wo^T + wob
        gemm_bt<EPI_RESID, true, float><<<dim3(6, TPAD / 128, 1), 256, 0, stream>>>(
            att, wo, wob, h, TPAD, Cdim, Cdim, 0, 0, 0, 0);

        ln_rows<bf16><<<dim3(TPAD), 256, 0, stream>>>(h, xn, g2, b2);

        // hid = gelu(xn @ m1^T + m1b)
        gemm_bt<EPI_GELU, true, bf16><<<dim3(Mdim / 128, TPAD / 128, 1), 256, 0, stream>>>(
            xn, m1, m1b, hid, TPAD, Mdim, Cdim, 0, 0, 0, 0);
        // h += hid @ m2^T + m2b
        gemm_bt<EPI_RESID, true, float><<<dim3(6, TPAD / 128, 1), 256, 0, stream>>>(
            hid, m2, m2b, h, TPAD, Cdim, Mdim, 0, 0, 0, 0);
    }

    // ---------------- head ----------------
    cls_pool<<<dim3((Bsz * Cdim + 255) / 256), 256, 0, stream>>>(h, cf);
    head_gemm<<<dim3((Bsz * NCls + 255) / 256), 256, 0, stream>>>(
        cf, head_w, head_b, (float*)d_out);
}